// Round 2
// 63.280 us; speedup vs baseline: 1.0263x; 1.0263x over previous
//
#include <hip/hip_runtime.h>
#include <math.h>

#define N 512
#define DIM 128
#define TT 32            // D-tile edge (i and j) in gram kernel
#define PADS 132         // padded LDS row stride (floats), float4-aligned
#define NTRI (16 * 17 / 2)   // 136 lower-triangle tile blocks

// ws layout: D[N*N] | sums[N] | cnts[N]

// Kernel A: D[i][j] = 18*max(0, 1 - dot(x_i,x_j)*rn_i*rn_j), SYMMETRIC:
// triangular grid of 136 blocks; off-diagonal tiles are computed once and
// written twice (direct + LDS-transposed mirror, reusing the xi staging buf).
// 2x2 register micro-tile with CONFLICT-AWARE mapping: thread (ty,tx) owns
// rows {ty, ty+16} x cols {tx, tx+16}.  B-row LDS word base = 132*tx ->
// start bank 4*tx mod 32 = 8 distinct bank-quads (2-way aliasing = free,
// m136), vs the old {2tx,2tx+1} mapping whose 264*tx mod 32 gave only 4
// quads (4-way conflict, 1.58x on the LDS pipe that bounds this kernel).
__global__ void __launch_bounds__(256) gram_kernel(const float* __restrict__ x,
                                                   float* __restrict__ D) {
    __shared__ float xi[TT * PADS];
    __shared__ float xj[TT * PADS];
    __shared__ float rnA[TT];
    __shared__ float rnB[TT];

    int t = threadIdx.x;

    // linear block index -> (bi, bj), bj <= bi (lower triangle)
    int b = blockIdx.x;
    int bi = (int)((sqrtf(8.0f * (float)b + 1.0f) - 1.0f) * 0.5f);
    while ((bi + 1) * (bi + 2) / 2 <= b) ++bi;   // float fixup
    while (bi * (bi + 1) / 2 > b) --bi;
    int bj = b - bi * (bi + 1) / 2;

    // stage both 32x128 tiles, coalesced float4 (4 per thread per tile)
    const float4* srcA = (const float4*)(x + bi * TT * DIM);
    const float4* srcB = (const float4*)(x + bj * TT * DIM);
    #pragma unroll
    for (int k = 0; k < (TT * DIM / 4) / 256; ++k) {
        int e = t + k * 256;
        int r = e >> 5, c4 = e & 31;       // 32 float4 per row
        *((float4*)(xi + r * PADS + 4 * c4)) = srcA[e];
        *((float4*)(xj + r * PADS + 4 * c4)) = srcB[e];
    }
    __syncthreads();

    // inverse norms: 4 threads/row x 64 rows (32 from each tile), shfl reduce
    {
        int quart = t & 3, r = t >> 2;     // r: 0..63
        const float* base = (r < TT) ? (xi + r * PADS) : (xj + (r - TT) * PADS);
        const float4* a = (const float4*)(base + quart * 32);
        float s0 = 0.0f, s1 = 0.0f;
        #pragma unroll
        for (int q = 0; q < 8; q += 2) {
            float4 a0 = a[q], a1 = a[q + 1];
            s0 += a0.x * a0.x + a0.y * a0.y + a0.z * a0.z + a0.w * a0.w;
            s1 += a1.x * a1.x + a1.y * a1.y + a1.z * a1.z + a1.w * a1.w;
        }
        float ss = s0 + s1;
        ss += __shfl_xor(ss, 1, 64);
        ss += __shfl_xor(ss, 2, 64);
        if (quart == 0) {
            if (r < TT) rnA[r] = rsqrtf(ss);
            else        rnB[r - TT] = rsqrtf(ss);
        }
    }
    __syncthreads();

    int tx = t & 15, ty = t >> 4;
    int i0 = ty, i1 = ty + 16, j0 = tx, j1 = tx + 16;
    float acc00 = 0.0f, acc01 = 0.0f, acc10 = 0.0f, acc11 = 0.0f;
    const float4* A0 = (const float4*)(xi + i0 * PADS);
    const float4* A1 = (const float4*)(xi + i1 * PADS);
    const float4* B0 = (const float4*)(xj + j0 * PADS);
    const float4* B1 = (const float4*)(xj + j1 * PADS);
    #pragma unroll 8
    for (int k4 = 0; k4 < DIM / 4; ++k4) {
        float4 a0 = A0[k4], a1 = A1[k4], b0 = B0[k4], b1 = B1[k4];
        acc00 += a0.x * b0.x + a0.y * b0.y + a0.z * b0.z + a0.w * b0.w;
        acc01 += a0.x * b1.x + a0.y * b1.y + a0.z * b1.z + a0.w * b1.w;
        acc10 += a1.x * b0.x + a1.y * b0.y + a1.z * b0.z + a1.w * b0.w;
        acc11 += a1.x * b1.x + a1.y * b1.y + a1.z * b1.z + a1.w * b1.w;
    }
    float ri0 = rnA[i0], ri1 = rnA[i1], rj0 = rnB[j0], rj1 = rnB[j1];
    // T[a][b] = D value at global (bi*32+a, bj*32+b)
    float t00 = 18.0f * fmaxf(0.0f, 1.0f - acc00 * ri0 * rj0);
    float t01 = 18.0f * fmaxf(0.0f, 1.0f - acc01 * ri0 * rj1);
    float t10 = 18.0f * fmaxf(0.0f, 1.0f - acc10 * ri1 * rj0);
    float t11 = 18.0f * fmaxf(0.0f, 1.0f - acc11 * ri1 * rj1);

    // direct write: 4 dword stores, each quarter-wave covers 64B contiguous
    {
        int gi0 = bi * TT + i0, gi1 = bi * TT + i1;
        int gj0 = bj * TT + j0, gj1 = bj * TT + j1;
        D[gi0 * N + gj0] = t00;
        D[gi0 * N + gj1] = t01;
        D[gi1 * N + gj0] = t10;
        D[gi1 * N + gj1] = t11;
    }

    if (bi != bj) {
        // mirror write via LDS transpose; xi is dead now, reuse as Tt[32][33]
        __syncthreads();                    // everyone done reading xi
        float* Tt = xi;                     // Tt[j][i] = T[i][j], stride 33
        Tt[j0 * 33 + i0] = t00;
        Tt[j1 * 33 + i0] = t01;
        Tt[j0 * 33 + i1] = t10;
        Tt[j1 * 33 + i1] = t11;
        __syncthreads();
        // mirror region: D[bj*32 + a][bi*32 + c] = T[c][a] = Tt[a][c]
        float m00 = Tt[i0 * 33 + j0], m01 = Tt[i0 * 33 + j1];
        float m10 = Tt[i1 * 33 + j0], m11 = Tt[i1 * 33 + j1];
        int ga0 = bj * TT + i0, ga1 = bj * TT + i1;
        int gb0 = bi * TT + j0, gb1 = bi * TT + j1;
        D[ga0 * N + gb0] = m00;
        D[ga0 * N + gb1] = m01;
        D[ga1 * N + gb0] = m10;
        D[ga1 * N + gb1] = m11;
    }
}

// Kernel B: block per anchor i. Read D row i (2 KB, coalesced), compact
// same/diff lists via ballot+popc prefix (NO LDS atomics: the old
// atomicAdd compaction serialized ~512 same-address DS atomics per block),
// precompute exp(sameD) once into LDS (was recomputed 256x per js),
// thread-per-k softplus (2 k/thread), per-block partial.
// NO grid-wide rendezvous: cg.sync (R5, +50us), same-address device atomics
// (R1, ~18us) and fence-heavy last-block-done (R8, +45us) all lose to a
// ~1us kernel boundary on this chip.
__global__ void __launch_bounds__(256) loss_kernel(const float* __restrict__ Dm,
                                                   const int* __restrict__ labels,
                                                   float* __restrict__ sums,
                                                   float* __restrict__ cnts) {
    __shared__ int   lab[N];
    __shared__ float sameD[N];
    __shared__ float diffD[N];
    __shared__ float esame[N];
    __shared__ int   cS[8], cD[8];
    __shared__ float red[4];

    int i = blockIdx.x, t = threadIdx.x;
    lab[t]       = labels[t];
    lab[t + 256] = labels[t + 256];
    float d0 = Dm[i * N + t];
    float d1 = Dm[i * N + t + 256];
    __syncthreads();

    int li = lab[i];
    int lane = t & 63, w = t >> 6;          // 4 waves; 8 compaction segments:
                                            // seg = w (j=t pass), w+4 (j=t+256)
    bool pS0 = (lab[t] == li) && (t != i);
    bool pD0 = (lab[t] != li);
    bool pS1 = (lab[t + 256] == li) && ((t + 256) != i);
    bool pD1 = (lab[t + 256] != li);
    unsigned long long bS0 = __ballot(pS0);
    unsigned long long bD0 = __ballot(pD0);
    unsigned long long bS1 = __ballot(pS1);
    unsigned long long bD1 = __ballot(pD1);
    if (lane == 0) {
        cS[w]     = __popcll(bS0); cD[w]     = __popcll(bD0);
        cS[w + 4] = __popcll(bS1); cD[w + 4] = __popcll(bD1);
    }
    __syncthreads();
    int baseS0 = 0, baseD0 = 0, baseS1 = 0, baseD1 = 0, ns = 0, nd = 0;
    #pragma unroll
    for (int s = 0; s < 8; ++s) {
        int cs = cS[s], cd = cD[s];
        if (s < w)     { baseS0 += cs; baseD0 += cd; }
        if (s < w + 4) { baseS1 += cs; baseD1 += cd; }
        ns += cs; nd += cd;
    }
    unsigned long long lt = (1ull << lane) - 1ull;
    if (pS0) sameD[baseS0 + __popcll(bS0 & lt)] = d0;
    if (pD0) diffD[baseD0 + __popcll(bD0 & lt)] = d0;
    if (pS1) sameD[baseS1 + __popcll(bS1 & lt)] = d1;
    if (pD1) diffD[baseD1 + __popcll(bD1 & lt)] = d1;
    __syncthreads();

    // exp(sameD) once; all 256 threads then only pay logs in the js loop
    if (t < ns)       esame[t]       = __expf(sameD[t]);
    if (t + 256 < ns) esame[t + 256] = __expf(sameD[t + 256]);
    __syncthreads();

    // softplus(s - k) = log(1 + e^s * e^-k); s in [0,36]: no fp32 overflow.
    // ln2 factored out: sum log2(...) and scale once at the end.
    float ek0 = (t < nd)       ? __expf(-diffD[t])       : 0.0f;  // 0 -> log(1)=0
    float ek1 = (t + 256 < nd) ? __expf(-diffD[t + 256]) : 0.0f;
    float lsum = 0.0f;
    for (int js = 0; js < ns; ++js) {
        float es = esame[js];              // LDS broadcast read
        lsum += __log2f(fmaf(es, ek0, 1.0f)) + __log2f(fmaf(es, ek1, 1.0f));
    }
    lsum *= 0.6931471805599453f;

    #pragma unroll
    for (int off = 32; off > 0; off >>= 1) lsum += __shfl_xor(lsum, off, 64);
    if ((t & 63) == 0) red[t >> 6] = lsum;
    __syncthreads();
    if (t == 0) {
        sums[i] = red[0] + red[1] + red[2] + red[3];
        cnts[i] = (float)(ns * nd);
    }
}

// Kernel C: reduce the 512 per-block partials (contention-free).
__global__ void __launch_bounds__(256) finalize_kernel(const float* __restrict__ sums,
                                                       const float* __restrict__ cnts,
                                                       float* __restrict__ out) {
    __shared__ float2 red[256];
    int t = threadIdx.x;
    float2 v;
    v.x = sums[t] + sums[t + 256];
    v.y = cnts[t] + cnts[t + 256];
    red[t] = v;
    __syncthreads();
    #pragma unroll
    for (int s = 128; s > 0; s >>= 1) {
        if (t < s) {
            red[t].x += red[t + s].x;
            red[t].y += red[t + s].y;
        }
        __syncthreads();
    }
    if (t == 0) out[0] = red[0].x / red[0].y;
}

extern "C" void kernel_launch(void* const* d_in, const int* in_sizes, int n_in,
                              void* d_out, int out_size, void* d_ws, size_t ws_size,
                              hipStream_t stream) {
    const float* x      = (const float*)d_in[0];
    const int*   labels = (const int*)d_in[1];
    float*       out    = (float*)d_out;

    float* Dm   = (float*)d_ws;       // 512*512 floats = 1 MB
    float* sums = Dm + N * N;         // 512 floats
    float* cnts = sums + N;           // 512 floats

    gram_kernel<<<NTRI, 256, 0, stream>>>(x, Dm);
    loss_kernel<<<N, 256, 0, stream>>>(Dm, labels, sums, cnts);
    finalize_kernel<<<1, 256, 0, stream>>>(sums, cnts, out);
}